// Round 2
// baseline (558.579 us; speedup 1.0000x reference)
//
#include <hip/hip_runtime.h>
#include <stdint.h>
#include <stddef.h>

#define DEV __device__ __forceinline__

using bf16x8 = __attribute__((ext_vector_type(8))) __bf16;
using f32x4  = __attribute__((ext_vector_type(4))) float;
typedef unsigned short u16;
typedef unsigned int   u32;

constexpr int CB    = 32;      // batch
constexpr int CN    = 1025;    // tokens (32*32+1)
constexpr int CD    = 512;     // dim
constexpr int CH    = 8;       // heads
constexpr int CHD   = 64;      // head dim
constexpr int MROWS = CB*CN;   // 32800
constexpr int MPAD  = 32896;   // 257*128
constexpr int NQKV  = 1536;
constexpr float L2E = 1.4426950408889634f;

DEV float bf2f(u16 u){ union{u32 i; float f;} x; x.i = ((u32)u)<<16; return x.f; }
DEV u16 f2bf(float f){ union{float f; u32 i;} x; x.f = f; u32 r = x.i + 0x7fffu + ((x.i>>16)&1u); return (u16)(r>>16); }

DEV f32x4 mfma16(bf16x8 a, bf16x8 b, f32x4 c){
  return __builtin_amdgcn_mfma_f32_16x16x32_bf16(a, b, c, 0, 0, 0);
}

typedef const __attribute__((address_space(1))) u32 GA;
typedef __attribute__((address_space(3))) u32 LA;
DEV void gload_lds16(const void* g, void* l){
  __builtin_amdgcn_global_load_lds((GA*)g, (LA*)l, 16, 0, 0);
}

// ---------------- cast & pad x -> bf16 (rows >= MROWS zeroed) ----------------
__global__ void cast_pad_x(const float* __restrict__ x, u16* __restrict__ xb){
  size_t stride = (size_t)gridDim.x * blockDim.x;
  size_t tot4  = (size_t)MPAD * CD / 4;
  size_t real4 = (size_t)MROWS * CD / 4;
  for(size_t i4 = (size_t)blockIdx.x*blockDim.x + threadIdx.x; i4 < tot4; i4 += stride){
    ushort4 o;
    if(i4 < real4){
      float4 f = reinterpret_cast<const float4*>(x)[i4];
      o.x=f2bf(f.x); o.y=f2bf(f.y); o.z=f2bf(f.z); o.w=f2bf(f.w);
    } else { o.x=0; o.y=0; o.z=0; o.w=0; }
    reinterpret_cast<ushort4*>(xb)[i4] = o;
  }
}

// ---------------- transpose-cast W (R x C f32 -> C x R bf16) ----------------
template<int R, int C>
__global__ void transpose_cast(const float* __restrict__ in, u16* __restrict__ out){
  __shared__ float t[32][33];
  int bx = blockIdx.x % (C/32);
  int by = blockIdx.x / (C/32);
  int c0 = bx*32, r0 = by*32;
  int j = threadIdx.x & 31, i0 = threadIdx.x >> 5;
  for(int i=i0;i<32;i+=8) t[i][j] = in[(size_t)(r0+i)*C + c0 + j];
  __syncthreads();
  for(int i=i0;i<32;i+=8) out[(size_t)(c0+i)*R + r0 + j] = f2bf(t[j][i]);
}

// ---------------- 128x128 bf16 MFMA GEMM,  C = A(MPADxK) * BT(NxK)^T + bias ----
// MODE 0: scatter into q/k/v head-layout bf16.  MODE 1: f32 row-major out.
template<int NCOL, int MODE>
__global__ __launch_bounds__(256)
void gemm_k(const u16* __restrict__ A, const u16* __restrict__ BT,
            const float* __restrict__ bias,
            u16* __restrict__ qo, u16* __restrict__ ko, u16* __restrict__ vo,
            float* __restrict__ outf)
{
  constexpr int K  = CD;
  constexpr int NT = NCOL/128;
  // bijective XCD remap (m204): A-tiles L2-local per XCD
  int nwg = gridDim.x, bid = blockIdx.x;
  int qg = nwg >> 3, rr = nwg & 7;
  int xc = bid & 7, ii = bid >> 3;
  int lt = (xc < rr ? xc*(qg+1) : rr*(qg+1) + (xc-rr)*qg) + ii;
  int mt = lt / NT, nt = lt - mt*NT;
  int m0 = mt*128, n0 = nt*128;

  __shared__ u16 lds[2*128*32];
  u16* As = lds;
  u16* Bs = lds + 128*32;
  int tid = threadIdx.x, wave = tid>>6, lane = tid&63;
  int l15 = lane&15, kg = lane>>4;
  int wm = wave&1, wn = wave>>1;
  int srow = lane>>2, sslot = lane&3;

  f32x4 acc[4][4];
  #pragma unroll
  for(int a0=0;a0<4;a0++)
    #pragma unroll
    for(int b0=0;b0<4;b0++) acc[a0][b0] = f32x4{0.f,0.f,0.f,0.f};

  for(int k0=0;k0<K;k0+=32){
    // stage: [128][32] bf16 tiles, 16B slots XOR-swizzled via pre-swizzled source
    #pragma unroll
    for(int it=0;it<2;it++){
      int chunk = wave*2 + it;
      int row = chunk*16 + srow;
      int sl = sslot ^ ((row>>1)&3);
      gload_lds16(A  + (size_t)(m0+row)*K + k0 + sl*8, As + chunk*512);
      gload_lds16(BT + (size_t)(n0+row)*K + k0 + sl*8, Bs + chunk*512);
    }
    __syncthreads();
    bf16x8 af[4], bfr[4];
    #pragma unroll
    for(int mi=0;mi<4;mi++){
      int row = wm*64 + mi*16 + l15;
      int sl = kg ^ ((row>>1)&3);
      af[mi] = *reinterpret_cast<const bf16x8*>((const char*)As + row*64 + sl*16);
    }
    #pragma unroll
    for(int ni=0;ni<4;ni++){
      int row = wn*64 + ni*16 + l15;
      int sl = kg ^ ((row>>1)&3);
      bfr[ni] = *reinterpret_cast<const bf16x8*>((const char*)Bs + row*64 + sl*16);
    }
    #pragma unroll
    for(int mi=0;mi<4;mi++)
      #pragma unroll
      for(int ni=0;ni<4;ni++)
        acc[mi][ni] = mfma16(af[mi], bfr[ni], acc[mi][ni]);
    __syncthreads();
  }

  #pragma unroll
  for(int mi=0;mi<4;mi++){
    #pragma unroll
    for(int i=0;i<4;i++){
      int r = m0 + wm*64 + mi*16 + kg*4 + i;
      if(r >= MROWS) continue;
      int bb = r / CN;
      int nn = r - bb*CN;
      #pragma unroll
      for(int ni=0;ni<4;ni++){
        int c = n0 + wn*64 + ni*16 + l15;
        float val = acc[mi][ni][i] + bias[c];
        if constexpr (MODE==0){
          int which = c >> 9;
          int h = (c>>6)&7, d = c&63;
          u16* dst = which==0 ? qo : (which==1 ? ko : vo);
          dst[(((size_t)bb*CH + h)*CN + nn)*CHD + d] = f2bf(val);
        } else {
          outf[(size_t)r*CD + c] = val;
        }
      }
    }
  }
}

// ---------------- zero the n=0 row of ev ----------------
__global__ void zero_ev(u16* __restrict__ ev){
  int i = blockIdx.x*256 + threadIdx.x;
  if(i < CB*CH*CHD){
    int bh = i >> 6, d = i & 63;
    ev[(size_t)bh*CN*CHD + d] = 0;
  }
}

// ---------------- per-(b,h): softmax stats over n + context C[p][q] ----------
__global__ __launch_bounds__(256)
void ctx_k(const u16* __restrict__ kb, const u16* __restrict__ vb, float* __restrict__ Cbuf){
  int blk = blockIdx.x; // b*8+h
  const u16* kbase = kb + (size_t)blk*CN*CHD;
  const u16* vbase = vb + (size_t)blk*CN*CHD;
  __shared__ float red[4][64];
  __shared__ float colmax[64];
  __shared__ float colrcp[64];
  __shared__ u16 ekT[64*128];  // [p][n] bf16, 16B slots XOR row&15
  __shared__ u16 vT [64*128];  // [q][n]
  int tid = threadIdx.x, wave = tid>>6, lane = tid&63;
  int l15 = lane&15, kg = lane>>4;

  // pass 1: column max over n (column = p = lane)
  float m = -3.0e38f;
  for(int n=wave; n<CN; n+=4) m = fmaxf(m, bf2f(kbase[(size_t)n*CHD + lane]));
  red[wave][lane] = m;
  __syncthreads();
  if(tid < 64) colmax[tid] = fmaxf(fmaxf(red[0][tid],red[1][tid]), fmaxf(red[2][tid],red[3][tid]));
  __syncthreads();
  // pass 2: column sum of exp
  float cm = colmax[lane];
  float s = 0.f;
  for(int n=wave; n<CN; n+=4) s += exp2f((bf2f(kbase[(size_t)n*CHD + lane]) - cm)*L2E);
  red[wave][lane] = s;
  __syncthreads();
  if(tid < 64) colrcp[tid] = 1.f/(red[0][tid]+red[1][tid]+red[2][tid]+red[3][tid]);
  __syncthreads();

  f32x4 acc[4];
  #pragma unroll
  for(int i=0;i<4;i++) acc[i] = f32x4{0.f,0.f,0.f,0.f};

  for(int n0=0; n0<CN; n0+=128){
    __syncthreads();
    // transpose-stage 128 n x 64 feat for both ek (exp folded) and v
    #pragma unroll
    for(int i=0;i<8;i++){
      int nl = lane*2 + (i&1);
      int p0 = (wave*4 + (i>>1))*4;
      int n  = n0 + nl;
      ushort4 kv, vv;
      if(n < CN){
        kv = *reinterpret_cast<const ushort4*>(kbase + (size_t)n*CHD + p0);
        vv = *reinterpret_cast<const ushort4*>(vbase + (size_t)n*CHD + p0);
      } else { kv.x=0;kv.y=0;kv.z=0;kv.w=0; vv.x=0;vv.y=0;vv.z=0;vv.w=0; }
      u16 ks[4] = {kv.x,kv.y,kv.z,kv.w};
      u16 vs[4] = {vv.x,vv.y,vv.z,vv.w};
      #pragma unroll
      for(int j=0;j<4;j++){
        int row = p0 + j;
        int slot = (nl>>3) ^ (row&15);
        float e = (n < CN) ? exp2f((bf2f(ks[j]) - colmax[row])*L2E) : 0.f;
        *(u16*)((char*)ekT + row*256 + slot*16 + (nl&7)*2) = f2bf(e);
        *(u16*)((char*)vT  + row*256 + slot*16 + (nl&7)*2) = vs[j];
      }
    }
    __syncthreads();
    // C[p][q] += sum_n ekT[p][n]*vT[q][n] ; wave owns q in [wave*16, wave*16+16)
    #pragma unroll
    for(int kk2=0;kk2<4;kk2++){
      int bcol = wave*16 + l15;
      int bslot = (kk2*4 + kg) ^ (bcol&15);
      bf16x8 bfr = *reinterpret_cast<const bf16x8*>((const char*)vT + bcol*256 + bslot*16);
      #pragma unroll
      for(int mi=0;mi<4;mi++){
        int arow = mi*16 + l15;
        int aslot = (kk2*4 + kg) ^ (arow&15);
        bf16x8 af = *reinterpret_cast<const bf16x8*>((const char*)ekT + arow*256 + aslot*16);
        acc[mi] = mfma16(af, bfr, acc[mi]);
      }
    }
  }
  #pragma unroll
  for(int mi=0;mi<4;mi++)
    #pragma unroll
    for(int i=0;i<4;i++){
      int pp = mi*16 + kg*4 + i;
      int qq = wave*16 + l15;
      Cbuf[(size_t)blk*4096 + pp*64 + qq] = acc[mi][i]*colrcp[pp];
    }
}

// ---------------- banded depthwise conv (bf16 LDS, x-padded) ----------------
template<int KS, int H0, int NHG, int BAND>
__global__ __launch_bounds__(512)
void conv_k(const u16* __restrict__ vb, const float* __restrict__ w,
            const float* __restrict__ bias, u16* __restrict__ ev)
{
  constexpr int R  = KS/2;
  constexpr int IW = 32 + 2*R;
  constexpr int IH = BAND + 2*R;
  constexpr int NB = 32/BAND;
  __shared__ u16 in_s[IH*IW*64];
  int band = blockIdx.x % NB;
  int bhi  = blockIdx.x / NB;
  int b = bhi / NHG;
  int hh = bhi - b*NHG;
  int h = H0 + hh;
  int y0 = band*BAND;
  const u16* src = vb + (((size_t)b*CH + h)*CN + 1)*CHD;
  int tid = threadIdx.x;
  int d = tid & 63;

  for(int e = tid; e < IH*IW*64; e += 512){
    int dd = e & 63;
    int rest = e >> 6;
    int xp = rest % IW;
    int yp = rest / IW;
    int gy = y0 + yp - R, gx = xp - R;
    u16 val = 0;
    if((unsigned)gy < 32u && (unsigned)gx < 32u) val = src[(size_t)(gy*32+gx)*CHD + dd];
    in_s[e] = val;
  }
  int c_local = hh*64 + d;
  float wreg[KS*KS];
  const float* wp = w + (size_t)c_local*KS*KS;
  #pragma unroll
  for(int i=0;i<KS*KS;i++) wreg[i] = wp[i];
  float bi = bias[c_local];
  __syncthreads();

  constexpr int GPR = 8/BAND;   // thread-groups per output row
  constexpr int XC  = 32/GPR;   // x pixels per group
  int grp = tid >> 6;
  int yl  = grp / GPR;
  int xs  = (grp - yl*GPR) * XC;
  u16* dst = ev + ((((size_t)b*CH + h)*CN) + 1 + (size_t)(y0+yl)*32)*CHD + d;
  for(int xi=0; xi<XC; xi++){
    int x = xs + xi;
    float acc = bi;
    #pragma unroll
    for(int ky=0;ky<KS;ky++)
      #pragma unroll
      for(int kx=0;kx<KS;kx++)
        acc = fmaf(wreg[ky*KS+kx], bf2f(in_s[((yl+ky)*IW + (x+kx))*64 + d]), acc);
    dst[(size_t)x*CHD] = f2bf(acc);
  }
}

// ---------------- A = scale*q@C + q.*ev  (per (b,h)), bf16 out --------------
__global__ __launch_bounds__(256)
void fuse_k(const u16* __restrict__ qb, const float* __restrict__ Cbuf,
            const u16* __restrict__ evb, u16* __restrict__ Aout)
{
  int blk = blockIdx.x;  // b*8+h
  int b = blk >> 3, h = blk & 7;
  __shared__ u16 Ct[64*64];   // [d][p] bf16, prescaled by 0.125, swizzled (rowB=128)
  __shared__ u16 qs[64*64];   // [n_local][p] bf16, swizzled
  __shared__ u16 evs[64*64];  // [n_local][d] bf16, linear
  int tid = threadIdx.x, wave = tid>>6, lane = tid&63;
  int l15 = lane&15, kg = lane>>4;

  for(int e = tid; e < 4096; e += 256){
    int pp = e >> 6, qq = e & 63;
    float cv = Cbuf[(size_t)blk*4096 + e];
    int slot = (pp>>3) ^ (qq&7);
    *(u16*)((char*)Ct + qq*128 + slot*16 + (pp&7)*2) = f2bf(cv*0.125f);
  }
  const u16* qbase  = qb  + (size_t)blk*CN*CHD;
  const u16* evbase = evb + (size_t)blk*CN*CHD;

  for(int n0=0; n0<CN; n0+=64){
    __syncthreads();
    #pragma unroll
    for(int it=0;it<2;it++){
      int cc = wave*2 + it;
      int row = cc*8 + (lane>>3);
      int P = lane&7;
      int sl = P ^ (row&7);
      gload_lds16(qbase  + (size_t)(n0+row)*CHD + sl*8, (char*)qs  + cc*1024);
      gload_lds16(evbase + (size_t)(n0+row)*CHD + P*8,  (char*)evs + cc*1024);
    }
    __syncthreads();
    f32x4 acc[4];
    #pragma unroll
    for(int i=0;i<4;i++) acc[i] = f32x4{0.f,0.f,0.f,0.f};
    #pragma unroll
    for(int kk2=0;kk2<2;kk2++){
      int arow = wave*16 + l15;
      int asl = (kk2*4+kg) ^ (arow&7);
      bf16x8 af = *reinterpret_cast<const bf16x8*>((const char*)qs + arow*128 + asl*16);
      #pragma unroll
      for(int ni=0;ni<4;ni++){
        int brow = ni*16 + l15;
        int bsl = (kk2*4+kg) ^ (brow&7);
        bf16x8 bfr = *reinterpret_cast<const bf16x8*>((const char*)Ct + brow*128 + bsl*16);
        acc[ni] = mfma16(af, bfr, acc[ni]);
      }
    }
    #pragma unroll
    for(int ni=0;ni<4;ni++){
      #pragma unroll
      for(int i=0;i<4;i++){
        int rl = wave*16 + kg*4 + i;
        int n = n0 + rl;
        if(n >= CN) continue;
        int dd = ni*16 + l15;
        int qsl = (dd>>3) ^ (rl&7);
        float qv  = bf2f(*(const u16*)((const char*)qs + rl*128 + qsl*16 + (dd&7)*2));
        float evv = bf2f(evs[rl*64 + dd]);
        float val = acc[ni][i] + qv*evv;
        Aout[((size_t)b*CN + n)*CD + h*64 + dd] = f2bf(val);
      }
    }
  }
}

// ---------------- host ----------------
extern "C" void kernel_launch(void* const* d_in, const int* in_sizes, int n_in,
                              void* d_out, int out_size, void* d_ws, size_t ws_size,
                              hipStream_t stream)
{
  const float* x    = (const float*)d_in[0];
  const float* Wqkv = (const float*)d_in[1];
  const float* bqkv = (const float*)d_in[2];
  const float* w3   = (const float*)d_in[3];
  const float* b3   = (const float*)d_in[4];
  const float* w5   = (const float*)d_in[5];
  const float* b5   = (const float*)d_in[6];
  const float* w7   = (const float*)d_in[7];
  const float* b7   = (const float*)d_in[8];
  const float* Wout = (const float*)d_in[9];
  const float* bout = (const float*)d_in[10];
  float* out = (float*)d_out;

  char* ws = (char*)d_ws;
  size_t off = 0;
  auto alloc = [&](size_t bytes)->void*{
    void* p = ws + off;
    off += (bytes + 255) & ~(size_t)255;
    return p;
  };
  u16* x_bf  = (u16*)alloc((size_t)MPAD*CD*2);            // aliased as A_bf later
  u16* WqkvT = (u16*)alloc((size_t)NQKV*CD*2);
  u16* WoutT = (u16*)alloc((size_t)CD*CD*2);
  u16* q_bf  = (u16*)alloc((size_t)CB*CH*CN*CHD*2);
  u16* k_bf  = (u16*)alloc((size_t)CB*CH*CN*CHD*2);
  u16* v_bf  = (u16*)alloc((size_t)CB*CH*CN*CHD*2);
  u16* ev_bf = (u16*)alloc((size_t)CB*CH*CN*CHD*2);
  float* Cb  = (float*)alloc((size_t)CB*CH*CHD*CHD*4);
  u16* A_bf  = x_bf;

  cast_pad_x<<<2048, 256, 0, stream>>>(x, x_bf);
  transpose_cast<CD, NQKV><<<(CD/32)*(NQKV/32), 256, 0, stream>>>(Wqkv, WqkvT);
  transpose_cast<CD, CD><<<(CD/32)*(CD/32), 256, 0, stream>>>(Wout, WoutT);
  gemm_k<NQKV, 0><<<(MPAD/128)*(NQKV/128), 256, 0, stream>>>(x_bf, WqkvT, bqkv, q_bf, k_bf, v_bf, nullptr);
  zero_ev<<<64, 256, 0, stream>>>(ev_bf);
  ctx_k<<<CB*CH, 256, 0, stream>>>(k_bf, v_bf, Cb);
  conv_k<3, 0, 2, 8><<<CB*2*4, 512, 0, stream>>>(v_bf, w3, b3, ev_bf);
  conv_k<5, 2, 3, 8><<<CB*3*4, 512, 0, stream>>>(v_bf, w5, b5, ev_bf);
  conv_k<7, 5, 3, 4><<<CB*3*8, 512, 0, stream>>>(v_bf, w7, b7, ev_bf);
  fuse_k<<<CB*CH, 256, 0, stream>>>(q_bf, Cb, ev_bf, A_bf);
  gemm_k<CD, 1><<<(MPAD/128)*(CD/128), 256, 0, stream>>>(A_bf, WoutT, bout, nullptr, nullptr, nullptr, out);

  (void)in_sizes; (void)n_in; (void)out_size; (void)ws_size;
}

// Round 6
// 447.691 us; speedup vs baseline: 1.2477x; 1.2477x over previous
//
#include <hip/hip_runtime.h>
#include <stdint.h>
#include <stddef.h>

#define DEV __device__ __forceinline__

using bf16x8 = __attribute__((ext_vector_type(8))) __bf16;
using f32x4  = __attribute__((ext_vector_type(4))) float;
typedef unsigned short u16;
typedef unsigned int   u32;
using u16x8 = __attribute__((ext_vector_type(8))) unsigned short;

constexpr int CB    = 32;      // batch
constexpr int CN    = 1025;    // tokens (32*32+1)
constexpr int CD    = 512;     // dim
constexpr int CH    = 8;       // heads
constexpr int CHD   = 64;      // head dim
constexpr int MROWS = CB*CN;   // 32800
constexpr int MPAD  = 32896;   // 257*128
constexpr int NQKV  = 1536;
constexpr int NCH   = 5;       // ctx n-chunks (5 x 256 >= 1025)
constexpr float L2E = 1.4426950408889634f;

DEV float bf2f(u16 u){ union{u32 i; float f;} x; x.i = ((u32)u)<<16; return x.f; }
DEV u16 f2bf(float f){ union{float f; u32 i;} x; x.f = f; u32 r = x.i + 0x7fffu + ((x.i>>16)&1u); return (u16)(r>>16); }

DEV f32x4 mfma16(bf16x8 a, bf16x8 b, f32x4 c){
  return __builtin_amdgcn_mfma_f32_16x16x32_bf16(a, b, c, 0, 0, 0);
}

typedef const __attribute__((address_space(1))) u32 GA;
typedef __attribute__((address_space(3))) u32 LA;
DEV void gload_lds16(const void* g, void* l){
  __builtin_amdgcn_global_load_lds((GA*)g, (LA*)l, 16, 0, 0);
}

// ---------------- cast & pad x -> bf16 (rows >= MROWS zeroed) ----------------
__global__ void cast_pad_x(const float* __restrict__ x, u16* __restrict__ xb){
  size_t stride = (size_t)gridDim.x * blockDim.x;
  size_t tot4  = (size_t)MPAD * CD / 4;
  size_t real4 = (size_t)MROWS * CD / 4;
  for(size_t i4 = (size_t)blockIdx.x*blockDim.x + threadIdx.x; i4 < tot4; i4 += stride){
    ushort4 o;
    if(i4 < real4){
      float4 f = reinterpret_cast<const float4*>(x)[i4];
      o.x=f2bf(f.x); o.y=f2bf(f.y); o.z=f2bf(f.z); o.w=f2bf(f.w);
    } else { o.x=0; o.y=0; o.z=0; o.w=0; }
    reinterpret_cast<ushort4*>(xb)[i4] = o;
  }
}

// ---------------- transpose-cast W (R x C f32 -> C x R bf16) ----------------
template<int R, int C>
__global__ void transpose_cast(const float* __restrict__ in, u16* __restrict__ out){
  __shared__ float t[32][33];
  int bx = blockIdx.x % (C/32);
  int by = blockIdx.x / (C/32);
  int c0 = bx*32, r0 = by*32;
  int j = threadIdx.x & 31, i0 = threadIdx.x >> 5;
  for(int i=i0;i<32;i+=8) t[i][j] = in[(size_t)(r0+i)*C + c0 + j];
  __syncthreads();
  for(int i=i0;i<32;i+=8) out[(size_t)(c0+i)*R + r0 + j] = f2bf(t[j][i]);
}

// ---------------- 128x128 bf16 MFMA GEMM,  C = A(MPADxK) * BT(NxK)^T + bias ----
// MODE 0: scatter into q/ek(=exp(k))/v head-layout bf16.  MODE 1: f32 row-major.
template<int NCOL, int MODE>
__global__ __launch_bounds__(256)
void gemm_k(const u16* __restrict__ A, const u16* __restrict__ BT,
            const float* __restrict__ bias,
            u16* __restrict__ qo, u16* __restrict__ ko, u16* __restrict__ vo,
            float* __restrict__ outf)
{
  constexpr int K  = CD;
  constexpr int NT = NCOL/128;
  int nwg = gridDim.x, bid = blockIdx.x;
  int qg = nwg >> 3, rr = nwg & 7;
  int xc = bid & 7, ii = bid >> 3;
  int lt = (xc < rr ? xc*(qg+1) : rr*(qg+1) + (xc-rr)*qg) + ii;
  int mt = lt / NT, nt = lt - mt*NT;
  int m0 = mt*128, n0 = nt*128;

  __shared__ u16 lds[2*128*32];
  u16* As = lds;
  u16* Bs = lds + 128*32;
  int tid = threadIdx.x, wave = tid>>6, lane = tid&63;
  int l15 = lane&15, kg = lane>>4;
  int wm = wave&1, wn = wave>>1;
  int srow = lane>>2, sslot = lane&3;

  f32x4 acc[4][4];
  #pragma unroll
  for(int a0=0;a0<4;a0++)
    #pragma unroll
    for(int b0=0;b0<4;b0++) acc[a0][b0] = f32x4{0.f,0.f,0.f,0.f};

  for(int k0=0;k0<K;k0+=32){
    #pragma unroll
    for(int it=0;it<2;it++){
      int chunk = wave*2 + it;
      int row = chunk*16 + srow;
      int sl = sslot ^ ((row>>1)&3);
      gload_lds16(A  + (size_t)(m0+row)*K + k0 + sl*8, As + chunk*512);
      gload_lds16(BT + (size_t)(n0+row)*K + k0 + sl*8, Bs + chunk*512);
    }
    __syncthreads();
    bf16x8 af[4], bfr[4];
    #pragma unroll
    for(int mi=0;mi<4;mi++){
      int row = wm*64 + mi*16 + l15;
      int sl = kg ^ ((row>>1)&3);
      af[mi] = *reinterpret_cast<const bf16x8*>((const char*)As + row*64 + sl*16);
    }
    #pragma unroll
    for(int ni=0;ni<4;ni++){
      int row = wn*64 + ni*16 + l15;
      int sl = kg ^ ((row>>1)&3);
      bfr[ni] = *reinterpret_cast<const bf16x8*>((const char*)Bs + row*64 + sl*16);
    }
    #pragma unroll
    for(int mi=0;mi<4;mi++)
      #pragma unroll
      for(int ni=0;ni<4;ni++)
        acc[mi][ni] = mfma16(af[mi], bfr[ni], acc[mi][ni]);
    __syncthreads();
  }

  #pragma unroll
  for(int mi=0;mi<4;mi++){
    #pragma unroll
    for(int i=0;i<4;i++){
      int r = m0 + wm*64 + mi*16 + kg*4 + i;
      if(r >= MROWS) continue;
      int bb = r / CN;
      int nn = r - bb*CN;
      #pragma unroll
      for(int ni=0;ni<4;ni++){
        int c = n0 + wn*64 + ni*16 + l15;
        float val = acc[mi][ni][i] + bias[c];
        if constexpr (MODE==0){
          int which = c >> 9;
          int h = (c>>6)&7, d = c&63;
          if(which==1) val = exp2f(val*L2E);   // ek = exp(k), shift-free softmax
          u16* dst = which==0 ? qo : (which==1 ? ko : vo);
          dst[(((size_t)bb*CH + h)*CN + nn)*CHD + d] = f2bf(val);
        } else {
          outf[(size_t)r*CD + c] = val;
        }
      }
    }
  }
}

// ---------------- zero the n=0 row of ev ----------------
__global__ void zero_ev(u16* __restrict__ ev){
  int i = blockIdx.x*256 + threadIdx.x;
  if(i < CB*CH*CHD){
    int bh = i >> 6, d = i & 63;
    ev[(size_t)bh*CN*CHD + d] = 0;
  }
}

// ------- ctx: per (bh, n-chunk of 256): partial C[p][q] and colsum[p] -------
__global__ __launch_bounds__(256)
void ctx_k(const u16* __restrict__ ekb, const u16* __restrict__ vb,
           float* __restrict__ Cpart, float* __restrict__ Spart)
{
  int blk = blockIdx.x;
  int bh = blk / NCH, t = blk - bh*NCH;
  const u16* ekbase = ekb + (size_t)bh*CN*CHD;
  const u16* vbase  = vb  + (size_t)bh*CN*CHD;
  __shared__ u16 ekT[64*128];   // [p][n] bf16, 16B slots XOR (n>>3)^(p&15)
  __shared__ u16 vT [64*128];   // [q][n]
  int tid = threadIdx.x, wave = tid>>6, lane = tid&63;
  int l15 = lane&15, kg = lane>>4;

  bf16x8 ones;
  #pragma unroll
  for(int j=0;j<8;j++) ones[j] = (__bf16)1.0f;

  f32x4 acc[4], accS[4];
  #pragma unroll
  for(int i=0;i<4;i++){ acc[i]=f32x4{0.f,0.f,0.f,0.f}; accS[i]=f32x4{0.f,0.f,0.f,0.f}; }

  for(int s=0;s<2;s++){
    int n0 = t*256 + s*128;
    __syncthreads();
    // transpose-stage 128 n x 64 feat (guarded; OOB rows -> 0)
    #pragma unroll
    for(int i=0;i<8;i++){
      int nl = lane*2 + (i&1);
      int p0 = wave*16 + (i>>1)*4;
      int n  = n0 + nl;
      ushort4 kv{0,0,0,0}, vv{0,0,0,0};
      if(n < CN){
        kv = *reinterpret_cast<const ushort4*>(ekbase + (size_t)n*CHD + p0);
        vv = *reinterpret_cast<const ushort4*>(vbase  + (size_t)n*CHD + p0);
      }
      u16 ks[4] = {kv.x,kv.y,kv.z,kv.w};
      u16 vs[4] = {vv.x,vv.y,vv.z,vv.w};
      #pragma unroll
      for(int j=0;j<4;j++){
        int p = p0 + j;
        int slot = (nl>>3) ^ (p&15);
        *(u16*)((char*)ekT + p*256 + slot*16 + (nl&7)*2) = ks[j];
        *(u16*)((char*)vT  + p*256 + slot*16 + (nl&7)*2) = vs[j];
      }
    }
    __syncthreads();
    #pragma unroll
    for(int kk2=0;kk2<4;kk2++){
      int bq = wave*16 + l15;
      bf16x8 bfr = *reinterpret_cast<const bf16x8*>((const char*)vT + bq*256 + (((kk2*4+kg)^(bq&15))*16));
      #pragma unroll
      for(int mi=0;mi<4;mi++){
        int p = mi*16 + l15;
        bf16x8 af = *reinterpret_cast<const bf16x8*>((const char*)ekT + p*256 + (((kk2*4+kg)^(p&15))*16));
        acc[mi]  = mfma16(af, bfr,  acc[mi]);
        accS[mi] = mfma16(af, ones, accS[mi]);
      }
    }
  }
  float* Cdst = Cpart + (size_t)blk*4096;
  #pragma unroll
  for(int mi=0;mi<4;mi++)
    #pragma unroll
    for(int i=0;i<4;i++){
      int pp = mi*16 + kg*4 + i;
      int qq = wave*16 + l15;
      Cdst[pp*64 + qq] = acc[mi][i];
      if(l15==0) Spart[(size_t)blk*64 + pp] = accS[mi][i];  // identical across waves
    }
}

// ------- combine: sum NCH partials, /S, *0.125, emit pre-swizzled bf16 Ct ----
__global__ __launch_bounds__(256)
void combine_k(const float* __restrict__ Cpart, const float* __restrict__ Spart,
               u16* __restrict__ Ctb)
{
  int bh = blockIdx.x;
  __shared__ float Cs[4096];
  __shared__ float rcpS[64];
  int tid = threadIdx.x;
  for(int e=tid; e<4096; e+=256){
    float s = 0.f;
    #pragma unroll
    for(int t=0;t<NCH;t++) s += Cpart[((size_t)bh*NCH+t)*4096 + e];
    Cs[e] = s;
  }
  if(tid < 64){
    float s = 0.f;
    #pragma unroll
    for(int t=0;t<NCH;t++) s += Spart[((size_t)bh*NCH+t)*64 + tid];
    rcpS[tid] = 0.125f / s;
  }
  __syncthreads();
  // Ct image layout (byte, within bh): qq*128 + ((pp>>3)^(qq&7))*16 + (pp&7)*2
  #pragma unroll
  for(int it2=0; it2<2; it2++){
    int qq = it2*32 + (tid>>3);
    int sg = tid & 7;
    int pb = (sg ^ (qq&7))*8;
    u16x8 pack;
    #pragma unroll
    for(int j=0;j<8;j++) pack[j] = f2bf(Cs[(pb+j)*64 + qq] * rcpS[pb+j]);
    *reinterpret_cast<u16x8*>(Ctb + (size_t)bh*4096 + qq*64 + sg*8) = pack;
  }
}

// ---------------- banded depthwise conv (bf16 LDS, x-padded) ----------------
template<int KS, int H0, int NHG, int BAND>
__global__ __launch_bounds__(512)
void conv_k(const u16* __restrict__ vb, const float* __restrict__ w,
            const float* __restrict__ bias, u16* __restrict__ ev)
{
  constexpr int R  = KS/2;
  constexpr int IW = 32 + 2*R;
  constexpr int IH = BAND + 2*R;
  constexpr int NB = 32/BAND;
  __shared__ u16 in_s[IH*IW*64];
  int band = blockIdx.x % NB;
  int bhi  = blockIdx.x / NB;
  int b = bhi / NHG;
  int hh = bhi - b*NHG;
  int h = H0 + hh;
  int y0 = band*BAND;
  const u16* src = vb + (((size_t)b*CH + h)*CN + 1)*CHD;
  int tid = threadIdx.x;
  int d = tid & 63;

  for(int e = tid; e < IH*IW*64; e += 512){
    int dd = e & 63;
    int rest = e >> 6;
    int xp = rest % IW;
    int yp = rest / IW;
    int gy = y0 + yp - R, gx = xp - R;
    u16 val = 0;
    if((unsigned)gy < 32u && (unsigned)gx < 32u) val = src[(size_t)(gy*32+gx)*CHD + dd];
    in_s[e] = val;
  }
  int c_local = hh*64 + d;
  float wreg[KS*KS];
  const float* wp = w + (size_t)c_local*KS*KS;
  #pragma unroll
  for(int i=0;i<KS*KS;i++) wreg[i] = wp[i];
  float bi = bias[c_local];
  __syncthreads();

  constexpr int GPR = 8/BAND;
  constexpr int XC  = 32/GPR;
  int grp = tid >> 6;
  int yl  = grp / GPR;
  int xs  = (grp - yl*GPR) * XC;
  u16* dst = ev + ((((size_t)b*CH + h)*CN) + 1 + (size_t)(y0+yl)*32)*CHD + d;
  for(int xi=0; xi<XC; xi++){
    int x = xs + xi;
    float acc = bi;
    #pragma unroll
    for(int ky=0;ky<KS;ky++)
      #pragma unroll
      for(int kx=0;kx<KS;kx++)
        acc = fmaf(wreg[ky*KS+kx], bf2f(in_s[((yl+ky)*IW + (x+kx))*64 + d]), acc);
    dst[(size_t)x*CHD] = f2bf(acc);
  }
}

// ------- fuse: A = q@Ct + q.*ev  per (bh, n-tile of 128), bf16 out ----------
__global__ __launch_bounds__(256)
void fuse_k(const u16* __restrict__ qb, const u16* __restrict__ Ctb,
            const u16* __restrict__ evb, u16* __restrict__ Aout)
{
  int blk = blockIdx.x;          // bh*9 + t
  int bh = blk / 9, t = blk - bh*9;
  int b = bh >> 3, h = bh & 7;
  int n0 = t*128;
  __shared__ u16 Ct[64*64];      // [q][p] bf16, slot XOR (p>>3)^(q&7)
  __shared__ u16 qs[128*64];     // [n][p] swizzled slot P^(row&7)
  __shared__ u16 evs[128*64];    // [n][d] same swizzle
  int tid = threadIdx.x, wave = tid>>6, lane = tid&63;
  int l15 = lane&15, kg = lane>>4;

  // stage Ct (linear copy of pre-swizzled image) + q/ev (pre-swizzled source)
  #pragma unroll
  for(int it=0; it<2; it++){
    int cc = wave*2 + it;
    gload_lds16(Ctb + (size_t)bh*4096 + cc*512 + lane*8, (char*)Ct + cc*1024);
  }
  const u16* qbase  = qb  + (size_t)bh*CN*CHD;
  const u16* evbase = evb + (size_t)bh*CN*CHD;
  #pragma unroll
  for(int it=0; it<4; it++){
    int cc = wave*4 + it;
    int row = cc*8 + (lane>>3);
    int P = lane&7;
    int sl = P ^ (row&7);
    gload_lds16(qbase  + (size_t)(n0+row)*CHD + sl*8, (char*)qs  + cc*1024);
    gload_lds16(evbase + (size_t)(n0+row)*CHD + sl*8, (char*)evs + cc*1024);
  }
  __syncthreads();

  f32x4 acc[2][4];
  #pragma unroll
  for(int mi=0;mi<2;mi++)
    #pragma unroll
    for(int ni=0;ni<4;ni++) acc[mi][ni] = f32x4{0.f,0.f,0.f,0.f};

  #pragma unroll
  for(int kk2=0;kk2<2;kk2++){
    bf16x8 af[2];
    #pragma unroll
    for(int mi=0;mi<2;mi++){
      int rl = wave*32 + mi*16 + l15;
      int asl = (kk2*4+kg) ^ (rl&7);
      af[mi] = *reinterpret_cast<const bf16x8*>((const char*)qs + rl*128 + asl*16);
    }
    #pragma unroll
    for(int ni=0;ni<4;ni++){
      int brow = ni*16 + l15;
      int bsl = (kk2*4+kg) ^ (brow&7);
      bf16x8 bfr = *reinterpret_cast<const bf16x8*>((const char*)Ct + brow*128 + bsl*16);
      #pragma unroll
      for(int mi=0;mi<2;mi++)
        acc[mi][ni] = mfma16(af[mi], bfr, acc[mi][ni]);
    }
  }

  #pragma unroll
  for(int mi=0;mi<2;mi++){
    #pragma unroll
    for(int i=0;i<4;i++){
      int rl = wave*32 + mi*16 + kg*4 + i;
      int n = n0 + rl;
      if(n >= CN) continue;
      #pragma unroll
      for(int ni=0;ni<4;ni++){
        int dd = ni*16 + l15;
        int sl2 = (dd>>3) ^ (rl&7);
        float qv  = bf2f(*(const u16*)((const char*)qs  + rl*128 + sl2*16 + (dd&7)*2));
        float evv = bf2f(*(const u16*)((const char*)evs + rl*128 + sl2*16 + (dd&7)*2));
        Aout[((size_t)b*CN + n)*CD + h*64 + dd] = f2bf(acc[mi][ni][i] + qv*evv);
      }
    }
  }
}

// ---------------- host ----------------
extern "C" void kernel_launch(void* const* d_in, const int* in_sizes, int n_in,
                              void* d_out, int out_size, void* d_ws, size_t ws_size,
                              hipStream_t stream)
{
  const float* x    = (const float*)d_in[0];
  const float* Wqkv = (const float*)d_in[1];
  const float* bqkv = (const float*)d_in[2];
  const float* w3   = (const float*)d_in[3];
  const float* b3   = (const float*)d_in[4];
  const float* w5   = (const float*)d_in[5];
  const float* b5   = (const float*)d_in[6];
  const float* w7   = (const float*)d_in[7];
  const float* b7   = (const float*)d_in[8];
  const float* Wout = (const float*)d_in[9];
  const float* bout = (const float*)d_in[10];
  float* out = (float*)d_out;

  char* ws = (char*)d_ws;
  size_t off = 0;
  auto alloc = [&](size_t bytes)->void*{
    void* p = ws + off;
    off += (bytes + 255) & ~(size_t)255;
    return p;
  };
  u16* x_bf  = (u16*)alloc((size_t)MPAD*CD*2);            // aliased as A_bf later
  u16* WqkvT = (u16*)alloc((size_t)NQKV*CD*2);
  u16* WoutT = (u16*)alloc((size_t)CD*CD*2);
  u16* q_bf  = (u16*)alloc((size_t)CB*CH*CN*CHD*2);
  u16* ek_bf = (u16*)alloc((size_t)CB*CH*CN*CHD*2);
  u16* v_bf  = (u16*)alloc((size_t)CB*CH*CN*CHD*2);
  u16* ev_bf = (u16*)alloc((size_t)CB*CH*CN*CHD*2);
  float* Cpart = (float*)alloc((size_t)CB*CH*NCH*4096*4); // 21 MB
  float* Spart = (float*)alloc((size_t)CB*CH*NCH*64*4);
  u16* Ctb   = (u16*)alloc((size_t)CB*CH*4096*2);         // swizzled bf16 Ct image
  u16* A_bf  = x_bf;

  cast_pad_x<<<2048, 256, 0, stream>>>(x, x_bf);
  transpose_cast<CD, NQKV><<<(CD/32)*(NQKV/32), 256, 0, stream>>>(Wqkv, WqkvT);
  transpose_cast<CD, CD><<<(CD/32)*(CD/32), 256, 0, stream>>>(Wout, WoutT);
  gemm_k<NQKV, 0><<<(MPAD/128)*(NQKV/128), 256, 0, stream>>>(x_bf, WqkvT, bqkv, q_bf, ek_bf, v_bf, nullptr);
  zero_ev<<<64, 256, 0, stream>>>(ev_bf);
  ctx_k<<<CB*CH*NCH, 256, 0, stream>>>(ek_bf, v_bf, Cpart, Spart);
  combine_k<<<CB*CH, 256, 0, stream>>>(Cpart, Spart, Ctb);
  conv_k<3, 0, 2, 8><<<CB*2*4, 512, 0, stream>>>(v_bf, w3, b3, ev_bf);
  conv_k<5, 2, 3, 8><<<CB*3*4, 512, 0, stream>>>(v_bf, w5, b5, ev_bf);
  conv_k<7, 5, 3, 4><<<CB*3*8, 512, 0, stream>>>(v_bf, w7, b7, ev_bf);
  fuse_k<<<CB*CH*9, 256, 0, stream>>>(q_bf, Ctb, ev_bf, A_bf);
  gemm_k<CD, 1><<<(MPAD/128)*(CD/128), 256, 0, stream>>>(A_bf, WoutT, bout, nullptr, nullptr, nullptr, out);

  (void)in_sizes; (void)n_in; (void)out_size; (void)ws_size;
}

// Round 8
// 387.397 us; speedup vs baseline: 1.4419x; 1.1556x over previous
//
#include <hip/hip_runtime.h>
#include <stdint.h>
#include <stddef.h>

#define DEV __device__ __forceinline__

using bf16x8 = __attribute__((ext_vector_type(8))) __bf16;
using f32x4  = __attribute__((ext_vector_type(4))) float;
typedef unsigned short u16;
typedef unsigned int   u32;
using u16x8 = __attribute__((ext_vector_type(8))) unsigned short;

constexpr int CB    = 32;      // batch
constexpr int CN    = 1025;    // tokens (32*32+1)
constexpr int CD    = 512;     // dim
constexpr int CH    = 8;       // heads
constexpr int CHD   = 64;      // head dim
constexpr int MROWS = CB*CN;   // 32800
constexpr int MPAD  = 32896;   // 257*128
constexpr int NQKV  = 1536;
constexpr int NCH   = 5;       // ctx n-chunks (5 x 256 >= 1025)
constexpr float L2E = 1.4426950408889634f;

DEV float bf2f(u16 u){ union{u32 i; float f;} x; x.i = ((u32)u)<<16; return x.f; }
DEV u16 f2bf(float f){ union{float f; u32 i;} x; x.f = f; u32 r = x.i + 0x7fffu + ((x.i>>16)&1u); return (u16)(r>>16); }

DEV f32x4 mfma16(bf16x8 a, bf16x8 b, f32x4 c){
  return __builtin_amdgcn_mfma_f32_16x16x32_bf16(a, b, c, 0, 0, 0);
}

typedef const __attribute__((address_space(1))) u32 GA;
typedef __attribute__((address_space(3))) u32 LA;
DEV void gload_lds16(const void* g, void* l){
  __builtin_amdgcn_global_load_lds((GA*)g, (LA*)l, 16, 0, 0);
}

// ---------------- cast & pad x -> bf16 (rows >= MROWS zeroed) ----------------
__global__ void cast_pad_x(const float* __restrict__ x, u16* __restrict__ xb){
  size_t stride = (size_t)gridDim.x * blockDim.x;
  size_t tot4  = (size_t)MPAD * CD / 4;
  size_t real4 = (size_t)MROWS * CD / 4;
  for(size_t i4 = (size_t)blockIdx.x*blockDim.x + threadIdx.x; i4 < tot4; i4 += stride){
    ushort4 o;
    if(i4 < real4){
      float4 f = reinterpret_cast<const float4*>(x)[i4];
      o.x=f2bf(f.x); o.y=f2bf(f.y); o.z=f2bf(f.z); o.w=f2bf(f.w);
    } else { o.x=0; o.y=0; o.z=0; o.w=0; }
    reinterpret_cast<ushort4*>(xb)[i4] = o;
  }
}

// ---------------- transpose-cast W (R x C f32 -> C x R bf16) ----------------
template<int R, int C>
__global__ void transpose_cast(const float* __restrict__ in, u16* __restrict__ out){
  __shared__ float t[32][33];
  int bx = blockIdx.x % (C/32);
  int by = blockIdx.x / (C/32);
  int c0 = bx*32, r0 = by*32;
  int j = threadIdx.x & 31, i0 = threadIdx.x >> 5;
  for(int i=i0;i<32;i+=8) t[i][j] = in[(size_t)(r0+i)*C + c0 + j];
  __syncthreads();
  for(int i=i0;i<32;i+=8) out[(size_t)(c0+i)*R + r0 + j] = f2bf(t[j][i]);
}

// ---- 128x128 bf16 MFMA GEMM, double-buffered K pipeline (T3-min 2-phase) ----
// MODE 0: scatter into q/ek(=exp(k))/v head-layout bf16.  MODE 1: f32 row-major.
template<int NCOL, int MODE>
__global__ __launch_bounds__(256)
void gemm_k(const u16* __restrict__ A, const u16* __restrict__ BT,
            const float* __restrict__ bias,
            u16* __restrict__ qo, u16* __restrict__ ko, u16* __restrict__ vo,
            float* __restrict__ outf)
{
  constexpr int K  = CD;
  constexpr int KSTEPS = K/32;     // 16
  constexpr int NT = NCOL/128;
  int nwg = gridDim.x, bid = blockIdx.x;
  int qg = nwg >> 3, rr = nwg & 7;
  int xc = bid & 7, ii = bid >> 3;
  int lt = (xc < rr ? xc*(qg+1) : rr*(qg+1) + (xc-rr)*qg) + ii;
  int mt = lt / NT, nt = lt - mt*NT;
  int m0 = mt*128, n0 = nt*128;

  __shared__ u16 lds[4*4096];      // [buf][A|B][128*32]
  int tid = threadIdx.x, wave = tid>>6, lane = tid&63;
  int l15 = lane&15, kg = lane>>4;
  int wm = wave&1, wn = wave>>1;
  int srow = lane>>2, sslot = lane&3;

  f32x4 acc[4][4];
  #pragma unroll
  for(int a0=0;a0<4;a0++)
    #pragma unroll
    for(int b0=0;b0<4;b0++) acc[a0][b0] = f32x4{0.f,0.f,0.f,0.f};

  // stage one K-tile (A+B) into buffer `buf`
  auto stage = [&](int buf, int k0){
    u16* As = lds + buf*8192;
    u16* Bs = As + 4096;
    #pragma unroll
    for(int it=0;it<2;it++){
      int chunk = wave*2 + it;
      int row = chunk*16 + srow;
      int sl = sslot ^ ((row>>1)&3);
      gload_lds16(A  + (size_t)(m0+row)*K + k0 + sl*8, As + chunk*512);
      gload_lds16(BT + (size_t)(n0+row)*K + k0 + sl*8, Bs + chunk*512);
    }
  };
  // ds_read + MFMA on buffer `buf` (compiler inserts fine-grained lgkmcnt)
  auto compute = [&](int buf){
    const u16* As = lds + buf*8192;
    const u16* Bs = As + 4096;
    bf16x8 af[4], bfr[4];
    #pragma unroll
    for(int mi=0;mi<4;mi++){
      int row = wm*64 + mi*16 + l15;
      int sl = kg ^ ((row>>1)&3);
      af[mi] = *reinterpret_cast<const bf16x8*>((const char*)As + row*64 + sl*16);
    }
    #pragma unroll
    for(int ni=0;ni<4;ni++){
      int row = wn*64 + ni*16 + l15;
      int sl = kg ^ ((row>>1)&3);
      bfr[ni] = *reinterpret_cast<const bf16x8*>((const char*)Bs + row*64 + sl*16);
    }
    #pragma unroll
    for(int mi=0;mi<4;mi++)
      #pragma unroll
      for(int ni=0;ni<4;ni++)
        acc[mi][ni] = mfma16(af[mi], bfr[ni], acc[mi][ni]);
  };

  // prologue: stage tile 0, drain, barrier
  stage(0, 0);
  asm volatile("s_waitcnt vmcnt(0)\n\ts_barrier" ::: "memory");
  // main loop: issue next-tile loads, compute current, drain+barrier
  int cur = 0;
  for(int t=0; t<KSTEPS-1; ++t){
    stage(cur^1, (t+1)*32);
    compute(cur);
    asm volatile("s_waitcnt vmcnt(0)\n\ts_barrier" ::: "memory");
    cur ^= 1;
  }
  compute(cur);   // tail: no prefetch, no barrier needed before epilogue

  #pragma unroll
  for(int mi=0;mi<4;mi++){
    #pragma unroll
    for(int i=0;i<4;i++){
      int r = m0 + wm*64 + mi*16 + kg*4 + i;
      if(r >= MROWS) continue;
      int bb = r / CN;
      int nn = r - bb*CN;
      #pragma unroll
      for(int ni=0;ni<4;ni++){
        int c = n0 + wn*64 + ni*16 + l15;
        float val = acc[mi][ni][i] + bias[c];
        if constexpr (MODE==0){
          int which = c >> 9;
          int h = (c>>6)&7, d = c&63;
          if(which==1) val = exp2f(val*L2E);   // ek = exp(k), shift-free softmax
          u16* dst = which==0 ? qo : (which==1 ? ko : vo);
          dst[(((size_t)bb*CH + h)*CN + nn)*CHD + d] = f2bf(val);
        } else {
          outf[(size_t)r*CD + c] = val;
        }
      }
    }
  }
}

// ---------------- zero the n=0 row of ev ----------------
__global__ void zero_ev(u16* __restrict__ ev){
  int i = blockIdx.x*256 + threadIdx.x;
  if(i < CB*CH*CHD){
    int bh = i >> 6, d = i & 63;
    ev[(size_t)bh*CN*CHD + d] = 0;
  }
}

// ------- ctx: per (bh, n-chunk of 256): partial C[p][q] and colsum[p] -------
__global__ __launch_bounds__(256)
void ctx_k(const u16* __restrict__ ekb, const u16* __restrict__ vb,
           float* __restrict__ Cpart, float* __restrict__ Spart)
{
  int blk = blockIdx.x;
  int bh = blk / NCH, t = blk - bh*NCH;
  const u16* ekbase = ekb + (size_t)bh*CN*CHD;
  const u16* vbase  = vb  + (size_t)bh*CN*CHD;
  __shared__ u16 ekT[64*128];   // [p][n] bf16, 16B slots XOR (n>>3)^(p&15)
  __shared__ u16 vT [64*128];   // [q][n]
  int tid = threadIdx.x, wave = tid>>6, lane = tid&63;
  int l15 = lane&15, kg = lane>>4;

  bf16x8 ones;
  #pragma unroll
  for(int j=0;j<8;j++) ones[j] = (__bf16)1.0f;

  f32x4 acc[4], accS[4];
  #pragma unroll
  for(int i=0;i<4;i++){ acc[i]=f32x4{0.f,0.f,0.f,0.f}; accS[i]=f32x4{0.f,0.f,0.f,0.f}; }

  for(int s=0;s<2;s++){
    int n0 = t*256 + s*128;
    __syncthreads();
    // transpose-stage 128 n x 64 feat; pack adjacent-n pairs -> ds_write_b32
    int n  = n0 + lane*2;
    int hi = (lane*2)>>3;
    int off = ((lane*2)&7)*2;           // byte offset in slot, 4B aligned
    #pragma unroll
    for(int i2=0;i2<4;i2++){
      int p0 = wave*16 + i2*4;
      ushort4 k0{0,0,0,0}, k1{0,0,0,0}, v0{0,0,0,0}, v1{0,0,0,0};
      if(n < CN){
        k0 = *reinterpret_cast<const ushort4*>(ekbase + (size_t)n*CHD + p0);
        v0 = *reinterpret_cast<const ushort4*>(vbase  + (size_t)n*CHD + p0);
      }
      if(n+1 < CN){
        k1 = *reinterpret_cast<const ushort4*>(ekbase + (size_t)(n+1)*CHD + p0);
        v1 = *reinterpret_cast<const ushort4*>(vbase  + (size_t)(n+1)*CHD + p0);
      }
      u16 ks0[4]={k0.x,k0.y,k0.z,k0.w}, ks1[4]={k1.x,k1.y,k1.z,k1.w};
      u16 vs0[4]={v0.x,v0.y,v0.z,v0.w}, vs1[4]={v1.x,v1.y,v1.z,v1.w};
      #pragma unroll
      for(int j=0;j<4;j++){
        int p = p0 + j;
        int slot = hi ^ (p&15);
        u32 kw = (u32)ks0[j] | ((u32)ks1[j]<<16);
        u32 vw = (u32)vs0[j] | ((u32)vs1[j]<<16);
        *(u32*)((char*)ekT + p*256 + slot*16 + off) = kw;
        *(u32*)((char*)vT  + p*256 + slot*16 + off) = vw;
      }
    }
    __syncthreads();
    #pragma unroll
    for(int kk2=0;kk2<4;kk2++){
      int bq = wave*16 + l15;
      bf16x8 bfr = *reinterpret_cast<const bf16x8*>((const char*)vT + bq*256 + (((kk2*4+kg)^(bq&15))*16));
      #pragma unroll
      for(int mi=0;mi<4;mi++){
        int p = mi*16 + l15;
        bf16x8 af = *reinterpret_cast<const bf16x8*>((const char*)ekT + p*256 + (((kk2*4+kg)^(p&15))*16));
        acc[mi]  = mfma16(af, bfr,  acc[mi]);
        accS[mi] = mfma16(af, ones, accS[mi]);
      }
    }
  }
  float* Cdst = Cpart + (size_t)blk*4096;
  #pragma unroll
  for(int mi=0;mi<4;mi++)
    #pragma unroll
    for(int i=0;i<4;i++){
      int pp = mi*16 + kg*4 + i;
      int qq = wave*16 + l15;
      Cdst[pp*64 + qq] = acc[mi][i];
      if(l15==0) Spart[(size_t)blk*64 + pp] = accS[mi][i];  // identical across waves
    }
}

// ------- combine: sum NCH partials, /S, *0.125, emit pre-swizzled bf16 Ct ----
__global__ __launch_bounds__(256)
void combine_k(const float* __restrict__ Cpart, const float* __restrict__ Spart,
               u16* __restrict__ Ctb)
{
  int bh = blockIdx.x;
  __shared__ float Cs[4096];
  __shared__ float rcpS[64];
  int tid = threadIdx.x;
  for(int e=tid; e<4096; e+=256){
    float s = 0.f;
    #pragma unroll
    for(int t=0;t<NCH;t++) s += Cpart[((size_t)bh*NCH+t)*4096 + e];
    Cs[e] = s;
  }
  if(tid < 64){
    float s = 0.f;
    #pragma unroll
    for(int t=0;t<NCH;t++) s += Spart[((size_t)bh*NCH+t)*64 + tid];
    rcpS[tid] = 0.125f / s;
  }
  __syncthreads();
  // Ct image layout (byte, within bh): qq*128 + ((pp>>3)^(qq&7))*16 + (pp&7)*2
  #pragma unroll
  for(int it2=0; it2<2; it2++){
    int qq = it2*32 + (tid>>3);
    int sg = tid & 7;
    int pb = (sg ^ (qq&7))*8;
    u16x8 pack;
    #pragma unroll
    for(int j=0;j<8;j++) pack[j] = f2bf(Cs[(pb+j)*64 + qq] * rcpS[pb+j]);
    *reinterpret_cast<u16x8*>(Ctb + (size_t)bh*4096 + qq*64 + sg*8) = pack;
  }
}

// ---------------- banded depthwise conv (bf16 LDS, x-padded) ----------------
template<int KS, int H0, int NHG, int BAND>
__global__ __launch_bounds__(512)
void conv_k(const u16* __restrict__ vb, const float* __restrict__ w,
            const float* __restrict__ bias, u16* __restrict__ ev)
{
  constexpr int R  = KS/2;
  constexpr int IW = 32 + 2*R;
  constexpr int IH = BAND + 2*R;
  constexpr int NB = 32/BAND;
  __shared__ u16 in_s[IH*IW*64];
  int band = blockIdx.x % NB;
  int bhi  = blockIdx.x / NB;
  int b = bhi / NHG;
  int hh = bhi - b*NHG;
  int h = H0 + hh;
  int y0 = band*BAND;
  const u16* src = vb + (((size_t)b*CH + h)*CN + 1)*CHD;
  int tid = threadIdx.x;
  int d = tid & 63;

  // vectorized staging: ushort4 along d (16 quads per pixel)
  for(int e4 = tid; e4 < IH*IW*16; e4 += 512){
    int dd4 = e4 & 15;
    int rest = e4 >> 4;
    int xp = rest % IW;
    int yp = rest / IW;
    int gy = y0 + yp - R, gx = xp - R;
    ushort4 val{0,0,0,0};
    if((unsigned)gy < 32u && (unsigned)gx < 32u)
      val = *reinterpret_cast<const ushort4*>(src + (size_t)(gy*32+gx)*CHD + dd4*4);
    *reinterpret_cast<ushort4*>(in_s + (yp*IW+xp)*64 + dd4*4) = val;
  }
  int c_local = hh*64 + d;
  float wreg[KS*KS];
  const float* wp = w + (size_t)c_local*KS*KS;
  #pragma unroll
  for(int i=0;i<KS*KS;i++) wreg[i] = wp[i];
  float bi = bias[c_local];
  __syncthreads();

  constexpr int GPR = 8/BAND;
  constexpr int XC  = 32/GPR;
  int grp = tid >> 6;
  int yl  = grp / GPR;
  int xs  = (grp - yl*GPR) * XC;
  u16* dst = ev + ((((size_t)b*CH + h)*CN) + 1 + (size_t)(y0+yl)*32)*CHD + d;
  for(int xi=0; xi<XC; xi++){
    int x = xs + xi;
    float acc = bi;
    #pragma unroll
    for(int ky=0;ky<KS;ky++)
      #pragma unroll
      for(int kx=0;kx<KS;kx++)
        acc = fmaf(wreg[ky*KS+kx], bf2f(in_s[((yl+ky)*IW + (x+kx))*64 + d]), acc);
    dst[(size_t)x*CHD] = f2bf(acc);
  }
}

// ------- fuse: A = q@Ct + q.*ev  per (bh, n-tile of 128), bf16 out ----------
__global__ __launch_bounds__(256)
void fuse_k(const u16* __restrict__ qb, const u16* __restrict__ Ctb,
            const u16* __restrict__ evb, u16* __restrict__ Aout)
{
  int blk = blockIdx.x;          // bh*9 + t
  int bh = blk / 9, t = blk - bh*9;
  int b = bh >> 3, h = bh & 7;
  int n0 = t*128;
  __shared__ u16 Ct[64*64];      // [q][p] bf16, slot XOR (p>>3)^(q&7)
  __shared__ u16 qs[128*64];     // [n][p] swizzled slot P^(row&7)
  __shared__ u16 evs[128*64];    // [n][d] same swizzle
  int tid = threadIdx.x, wave = tid>>6, lane = tid&63;
  int l15 = lane&15, kg = lane>>4;

  // stage Ct (linear copy of pre-swizzled image) + q/ev (pre-swizzled source)
  #pragma unroll
  for(int it=0; it<2; it++){
    int cc = wave*2 + it;
    gload_lds16(Ctb + (size_t)bh*4096 + cc*512 + lane*8, (char*)Ct + cc*1024);
  }
  const u16* qbase  = qb  + (size_t)bh*CN*CHD;
  const u16* evbase = evb + (size_t)bh*CN*CHD;
  #pragma unroll
  for(int it=0; it<4; it++){
    int cc = wave*4 + it;
    int row = cc*8 + (lane>>3);
    int P = lane&7;
    int sl = P ^ (row&7);
    gload_lds16(qbase  + (size_t)(n0+row)*CHD + sl*8, (char*)qs  + cc*1024);
    gload_lds16(evbase + (size_t)(n0+row)*CHD + sl*8, (char*)evs + cc*1024);
  }
  __syncthreads();

  f32x4 acc[2][4];
  #pragma unroll
  for(int mi=0;mi<2;mi++)
    #pragma unroll
    for(int ni=0;ni<4;ni++) acc[mi][ni] = f32x4{0.f,0.f,0.f,0.f};

  #pragma unroll
  for(int kk2=0;kk2<2;kk2++){
    bf16x8 af[2];
    #pragma unroll
    for(int mi=0;mi<2;mi++){
      int rl = wave*32 + mi*16 + l15;
      int asl = (kk2*4+kg) ^ (rl&7);
      af[mi] = *reinterpret_cast<const bf16x8*>((const char*)qs + rl*128 + asl*16);
    }
    #pragma unroll
    for(int ni=0;ni<4;ni++){
      int brow = ni*16 + l15;
      int bsl = (kk2*4+kg) ^ (brow&7);
      bf16x8 bfr = *reinterpret_cast<const bf16x8*>((const char*)Ct + brow*128 + bsl*16);
      #pragma unroll
      for(int mi=0;mi<2;mi++)
        acc[mi][ni] = mfma16(af[mi], bfr, acc[mi][ni]);
    }
  }

  #pragma unroll
  for(int mi=0;mi<2;mi++){
    #pragma unroll
    for(int i=0;i<4;i++){
      int rl = wave*32 + mi*16 + kg*4 + i;
      int n = n0 + rl;
      if(n >= CN) continue;
      #pragma unroll
      for(int ni=0;ni<4;ni++){
        int dd = ni*16 + l15;
        int sl2 = (dd>>3) ^ (rl&7);
        float qv  = bf2f(*(const u16*)((const char*)qs  + rl*128 + sl2*16 + (dd&7)*2));
        float evv = bf2f(*(const u16*)((const char*)evs + rl*128 + sl2*16 + (dd&7)*2));
        Aout[((size_t)b*CN + n)*CD + h*64 + dd] = f2bf(acc[mi][ni][i] + qv*evv);
      }
    }
  }
}

// ---------------- host ----------------
extern "C" void kernel_launch(void* const* d_in, const int* in_sizes, int n_in,
                              void* d_out, int out_size, void* d_ws, size_t ws_size,
                              hipStream_t stream)
{
  const float* x    = (const float*)d_in[0];
  const float* Wqkv = (const float*)d_in[1];
  const float* bqkv = (const float*)d_in[2];
  const float* w3   = (const float*)d_in[3];
  const float* b3   = (const float*)d_in[4];
  const float* w5   = (const float*)d_in[5];
  const float* b5   = (const float*)d_in[6];
  const float* w7   = (const float*)d_in[7];
  const float* b7   = (const float*)d_in[8];
  const float* Wout = (const float*)d_in[9];
  const float* bout = (const float*)d_in[10];
  float* out = (float*)d_out;

  char* ws = (char*)d_ws;
  size_t off = 0;
  auto alloc = [&](size_t bytes)->void*{
    void* p = ws + off;
    off += (bytes + 255) & ~(size_t)255;
    return p;
  };
  u16* x_bf  = (u16*)alloc((size_t)MPAD*CD*2);            // aliased as A_bf later
  u16* WqkvT = (u16*)alloc((size_t)NQKV*CD*2);
  u16* WoutT = (u16*)alloc((size_t)CD*CD*2);
  u16* q_bf  = (u16*)alloc((size_t)CB*CH*CN*CHD*2);
  u16* ek_bf = (u16*)alloc((size_t)CB*CH*CN*CHD*2);
  u16* v_bf  = (u16*)alloc((size_t)CB*CH*CN*CHD*2);
  u16* ev_bf = (u16*)alloc((size_t)CB*CH*CN*CHD*2);
  float* Cpart = (float*)alloc((size_t)CB*CH*NCH*4096*4); // 21 MB
  float* Spart = (float*)alloc((size_t)CB*CH*NCH*64*4);
  u16* Ctb   = (u16*)alloc((size_t)CB*CH*4096*2);         // swizzled bf16 Ct image
  u16* A_bf  = x_bf;

  cast_pad_x<<<2048, 256, 0, stream>>>(x, x_bf);
  transpose_cast<CD, NQKV><<<(CD/32)*(NQKV/32), 256, 0, stream>>>(Wqkv, WqkvT);
  transpose_cast<CD, CD><<<(CD/32)*(CD/32), 256, 0, stream>>>(Wout, WoutT);
  gemm_k<NQKV, 0><<<(MPAD/128)*(NQKV/128), 256, 0, stream>>>(x_bf, WqkvT, bqkv, q_bf, ek_bf, v_bf, nullptr);
  zero_ev<<<64, 256, 0, stream>>>(ev_bf);
  ctx_k<<<CB*CH*NCH, 256, 0, stream>>>(ek_bf, v_bf, Cpart, Spart);
  combine_k<<<CB*CH, 256, 0, stream>>>(Cpart, Spart, Ctb);
  conv_k<3, 0, 2, 8><<<CB*2*4, 512, 0, stream>>>(v_bf, w3, b3, ev_bf);
  conv_k<5, 2, 3, 8><<<CB*3*4, 512, 0, stream>>>(v_bf, w5, b5, ev_bf);
  conv_k<7, 5, 3, 4><<<CB*3*8, 512, 0, stream>>>(v_bf, w7, b7, ev_bf);
  fuse_k<<<CB*CH*9, 256, 0, stream>>>(q_bf, Ctb, ev_bf, A_bf);
  gemm_k<CD, 1><<<(MPAD/128)*(CD/128), 256, 0, stream>>>(A_bf, WoutT, bout, nullptr, nullptr, nullptr, out);

  (void)in_sizes; (void)n_in; (void)out_size; (void)ws_size;
}